// Round 1
// baseline (267.343 us; speedup 1.0000x reference)
//
#include <hip/hip_runtime.h>
#include <cstdint>
#include <cstddef>

typedef __attribute__((ext_vector_type(8))) _Float16 f16x8;
typedef __attribute__((ext_vector_type(4))) _Float16 f16x4;
typedef __attribute__((ext_vector_type(4))) float f32x4;

#define MFMA_16x16x32(a, b, c) __builtin_amdgcn_mfma_f32_16x16x32_f16((a), (b), (c), 0, 0, 0)

static constexpr int kB = 2, kS = 2048, kDim = 1024, kH = 16, kD = 64;
static constexpr int kM = kB * kS;  // 4096 rows total
// 1/sqrt(64) * log2(e), folded into Q at projection time
static constexpr float kQScale = 0.125f * 1.44269504088896340736f;
// -1e6 * log2(e): mask penalty in exp2 domain, computed inline in attn
static constexpr float kPenC = 1.44269504088896340736e6f;

// Raw workgroup barrier: drain only LDS ops (lgkmcnt), NOT vmcnt.
// __syncthreads() lowers to s_waitcnt vmcnt(0) lgkmcnt(0); the vmcnt(0)
// drain kills register prefetch across the barrier. LDS visibility across
// waves only needs each wave's ds ops retired (lgkmcnt) + s_barrier.
// "memory" clobber = compiler-level fence so LDS values aren't cached across.
__device__ __forceinline__ void wg_barrier_lds() {
  asm volatile("s_waitcnt lgkmcnt(0)" ::: "memory");
  __builtin_amdgcn_s_barrier();
}

// ---------------- elementwise f32 -> f16 ----------------
__global__ void cvt_f32_to_f16(const float* __restrict__ in, _Float16* __restrict__ out, int n8) {
  int i = blockIdx.x * blockDim.x + threadIdx.x;
  if (i >= n8) return;
  const float4* p = (const float4*)in + (size_t)i * 2;
  float4 a = p[0], b = p[1];
  f16x8 h;
  h[0] = (_Float16)a.x; h[1] = (_Float16)a.y; h[2] = (_Float16)a.z; h[3] = (_Float16)a.w;
  h[4] = (_Float16)b.x; h[5] = (_Float16)b.y; h[6] = (_Float16)b.z; h[7] = (_Float16)b.w;
  ((f16x8*)out)[i] = h;
}

// ------------- W [K][N] f32  ->  Wt [N][K] f16 (4 matrices) -------------
__global__ void transpose_cvt_w(const float* __restrict__ w0, const float* __restrict__ w1,
                                const float* __restrict__ w2, const float* __restrict__ w3,
                                _Float16* __restrict__ o0, _Float16* __restrict__ o1,
                                _Float16* __restrict__ o2, _Float16* __restrict__ o3) {
  const float* w; _Float16* o;
  switch (blockIdx.z) {
    case 0: w = w0; o = o0; break;
    case 1: w = w1; o = o1; break;
    case 2: w = w2; o = o2; break;
    default: w = w3; o = o3; break;
  }
  __shared__ alignas(16) _Float16 tile[64][72];
  const int kt = blockIdx.x * 64;
  const int nt = blockIdx.y * 64;
  const int tr = threadIdx.x >> 4;
  const int tc = threadIdx.x & 15;
#pragma unroll
  for (int rr = 0; rr < 4; ++rr) {
    int r = rr * 16 + tr;
    float4 v = *(const float4*)&w[(size_t)(kt + r) * kDim + nt + tc * 4];
    f16x4 hv;
    hv[0] = (_Float16)v.x; hv[1] = (_Float16)v.y; hv[2] = (_Float16)v.z; hv[3] = (_Float16)v.w;
    *(f16x4*)&tile[r][tc * 4] = hv;
  }
  __syncthreads();
#pragma unroll
  for (int rr = 0; rr < 4; ++rr) {
    int nl = rr * 16 + tr;
    f16x4 hv;
    hv[0] = tile[tc * 4 + 0][nl];
    hv[1] = tile[tc * 4 + 1][nl];
    hv[2] = tile[tc * 4 + 2][nl];
    hv[3] = tile[tc * 4 + 3][nl];
    *(f16x4*)&o[(size_t)(nt + nl) * kDim + kt + tc * 4] = hv;
  }
}

// ------------- QKV projection GEMM (BK=64, double-buffered LDS, 1 barrier/iter) -------------
__global__ __launch_bounds__(256, 2) void gemm_qkv(
    const _Float16* __restrict__ A,
    const _Float16* __restrict__ wt0, const _Float16* __restrict__ wt1, const _Float16* __restrict__ wt2,
    const float* __restrict__ bias0, const float* __restrict__ bias1, const float* __restrict__ bias2,
    _Float16* __restrict__ oq, _Float16* __restrict__ ok, _Float16* __restrict__ ov) {
  const _Float16* Bt; const float* bias; _Float16* out;
  switch (blockIdx.z) {
    case 0: Bt = wt0; bias = bias0; out = oq; break;
    case 1: Bt = wt1; bias = bias1; out = ok; break;
    default: Bt = wt2; bias = bias2; out = ov; break;
  }
  __shared__ alignas(16) _Float16 As[2][128 * 72];
  __shared__ alignas(16) _Float16 Bs[2][128 * 72];
  const int tid = threadIdx.x;
  const int lane = tid & 63;
  const int wave = tid >> 6;
  const int wm = wave & 1, wn = wave >> 1;
  const int l15 = lane & 15, quad = lane >> 4;
  const int m0 = blockIdx.x * 128, n0 = blockIdx.y * 128;

  const int srow = tid >> 3;             // staging row (tid + 256*i -> row = srow + 32*i)
  const int skc = (tid & 7) * 8;         // staging k-offset

  f32x4 acc[4][4] = {};
  f16x8 ra[4], rb[4];

  // prologue: stage k0=0 into buffer 0
#pragma unroll
  for (int i = 0; i < 4; ++i) {
    int row = srow + 32 * i;
    ra[i] = *(const f16x8*)&A[(size_t)(m0 + row) * kDim + skc];
    rb[i] = *(const f16x8*)&Bt[(size_t)(n0 + row) * kDim + skc];
  }
#pragma unroll
  for (int i = 0; i < 4; ++i) {
    int row = srow + 32 * i;
    *(f16x8*)&As[0][row * 72 + skc] = ra[i];
    *(f16x8*)&Bs[0][row * 72 + skc] = rb[i];
  }

  for (int kt = 0; kt < 16; ++kt) {
    const int cur = kt & 1;
    // issue next tile's global loads early; raw barrier below does NOT drain
    // vmcnt, so these stay in flight under the MFMA phase.
    if (kt + 1 < 16) {
      int k0 = (kt + 1) * 64;
#pragma unroll
      for (int i = 0; i < 4; ++i) {
        int row = srow + 32 * i;
        ra[i] = *(const f16x8*)&A[(size_t)(m0 + row) * kDim + k0 + skc];
        rb[i] = *(const f16x8*)&Bt[(size_t)(n0 + row) * kDim + k0 + skc];
      }
    }
    wg_barrier_lds();  // writes to buffer `cur` (prev iter / prologue) complete
#pragma unroll
    for (int kk = 0; kk < 2; ++kk) {
      f16x8 af[4], bf[4];
#pragma unroll
      for (int t = 0; t < 4; ++t) af[t] = *(const f16x8*)&As[cur][(wm * 64 + t * 16 + l15) * 72 + kk * 32 + quad * 8];
#pragma unroll
      for (int t = 0; t < 4; ++t) bf[t] = *(const f16x8*)&Bs[cur][(wn * 64 + t * 16 + l15) * 72 + kk * 32 + quad * 8];
#pragma unroll
      for (int i = 0; i < 4; ++i)
#pragma unroll
        for (int j = 0; j < 4; ++j)
          acc[i][j] = MFMA_16x16x32(af[i], bf[j], acc[i][j]);
    }
    if (kt + 1 < 16) {
#pragma unroll
      for (int i = 0; i < 4; ++i) {
        int row = srow + 32 * i;
        *(f16x8*)&As[cur ^ 1][row * 72 + skc] = ra[i];
        *(f16x8*)&Bs[cur ^ 1][row * 72 + skc] = rb[i];
      }
    }
  }

  const int mbase = m0 + wm * 64 + quad * 4;
  const int nbase = n0 + wn * 64 + l15;
  if (blockIdx.z == 2) {
#pragma unroll
    for (int j = 0; j < 4; ++j) {
      int n = nbase + j * 16;
      float bv = bias[n];
      int h = n >> 6, d = n & 63;
#pragma unroll
      for (int i = 0; i < 4; ++i) {
        int m = mbase + i * 16;
        int b = m >> 11, s = m & (kS - 1);
        f16x4 hv;
#pragma unroll
        for (int r = 0; r < 4; ++r) hv[r] = (_Float16)(acc[i][j][r] + bv);
        *(f16x4*)&out[((size_t)((b * kH + h) * kD + d)) * kS + s] = hv;
      }
    }
  } else {
    const float osc = (blockIdx.z == 0) ? kQScale : 1.0f;
#pragma unroll
    for (int j = 0; j < 4; ++j) {
      int n = nbase + j * 16;
      float bv = bias[n];
      int h = n >> 6, d = n & 63;
#pragma unroll
      for (int i = 0; i < 4; ++i) {
        int mrow = mbase + i * 16;
#pragma unroll
        for (int r = 0; r < 4; ++r) {
          int m = mrow + r;
          int b = m >> 11, s = m & (kS - 1);
          out[(size_t)(((b * kH + h) * kS) + s) * kD + d] = (_Float16)((acc[i][j][r] + bv) * osc);
        }
      }
    }
  }
}

// ------------- flash attention, S^T formulation -------------
// v2 changes vs 75.4us baseline:
//  - V fragments read DIRECTLY from global [d][s] layout (drop Vs LDS staging:
//    -17.4KB LDS, -16KB/wave/iter LDS reads; V is L2-resident per XCD swizzle)
//  - K tile register-prefetched across raw lgkm-only barriers (latency hidden)
//  - mask penalty computed inline from mask (mask_penalty kernel dropped)
//  - per-colt S^T -> exp -> Pt store (live s regs 8 instead of 64)
//  - XCD-bijective swizzle: each XCD owns 4 consecutive bh (2MB K/V <= 4MB L2)
__global__ __launch_bounds__(256, 2) void attn(
    const _Float16* __restrict__ Q, const _Float16* __restrict__ K,
    const _Float16* __restrict__ V, const float* __restrict__ mask,
    _Float16* __restrict__ ctx) {
  // 512 blocks, 8 XCDs -> 64 blocks/XCD, bh-major within an XCD
  const int id = blockIdx.x;
  const int logical = (id & 7) * 64 + (id >> 3);
  const int bh = logical >> 4;    // 0..31
  const int qblk = logical & 15;  // 0..15
  const int b = bh >> 4;
  const int q0 = qblk * 128;
  const int tid = threadIdx.x, lane = tid & 63, wave = tid >> 6;
  const int l15 = lane & 15, quad = lane >> 4;

  __shared__ alignas(16) _Float16 Ks[128 * 72];       // [key][d]
  __shared__ alignas(16) _Float16 Pt[4][32 * 136];    // per-wave P^T [q][key]

  const _Float16* Qh = Q + (size_t)bh * kS * kD;
  const _Float16* Kh = K + (size_t)bh * kS * kD;
  const _Float16* Vh = V + (size_t)bh * kS * kD;  // [d][s]
  const float* mrow = mask + b * kS;

  f16x8 qf[2][2];
#pragma unroll
  for (int t = 0; t < 2; ++t) {
    int qrow = q0 + wave * 32 + t * 16 + l15;
#pragma unroll
    for (int kk = 0; kk < 2; ++kk)
      qf[t][kk] = *(const f16x8*)&Qh[(size_t)qrow * kD + kk * 32 + quad * 8];
  }

  f32x4 o_acc[2][4] = {};   // O^T: [t][d-tile], C-layout (row=d, col=q)
  float l_part[2] = {0.0f, 0.0f};

  const int srow = tid >> 3;       // 0..31
  const int skc = (tid & 7) * 8;

  // prologue: prefetch first K tile into registers
  f16x8 kreg[4];
#pragma unroll
  for (int i = 0; i < 4; ++i)
    kreg[i] = *(const f16x8*)&Kh[(size_t)(srow + 32 * i) * kD + skc];

  for (int it = 0; it < 16; ++it) {
    const int kb = it * 128;
    wg_barrier_lds();   // all waves done reading Ks from previous iter
#pragma unroll
    for (int i = 0; i < 4; ++i)
      *(f16x8*)&Ks[(srow + 32 * i) * 72 + skc] = kreg[i];
    if (it + 1 < 16) {  // issue next K tile; flies under compute (no vmcnt drain)
#pragma unroll
      for (int i = 0; i < 4; ++i)
        kreg[i] = *(const f16x8*)&Kh[(size_t)(kb + 128 + srow + 32 * i) * kD + skc];
    }
    wg_barrier_lds();   // Ks ready

    // S^T = K Q^T per 16-key column-tile; exp2 with inline mask penalty; Pt store
#pragma unroll
    for (int colt = 0; colt < 8; ++colt) {
      f16x8 kf0 = *(const f16x8*)&Ks[(colt * 16 + l15) * 72 + quad * 8];
      f16x8 kf1 = *(const f16x8*)&Ks[(colt * 16 + l15) * 72 + 32 + quad * 8];
      f32x4 s0 = {}, s1 = {};
      s0 = MFMA_16x16x32(kf0, qf[0][0], s0);
      s0 = MFMA_16x16x32(kf1, qf[0][1], s0);
      s1 = MFMA_16x16x32(kf0, qf[1][0], s1);
      s1 = MFMA_16x16x32(kf1, qf[1][1], s1);
      f32x4 mv = *(const f32x4*)&mrow[kb + colt * 16 + quad * 4];
      f16x4 ph0, ph1;
#pragma unroll
      for (int r = 0; r < 4; ++r) {
        float pn = (mv[r] - 1.0f) * kPenC;   // == -1e6*(1-m)*log2e
        float p0 = __builtin_exp2f(s0[r] + pn);
        float p1 = __builtin_exp2f(s1[r] + pn);
        l_part[0] += p0;
        l_part[1] += p1;
        ph0[r] = (_Float16)p0;
        ph1[r] = (_Float16)p1;
      }
      *(f16x4*)&Pt[wave][(l15) * 136 + colt * 16 + quad * 4] = ph0;
      *(f16x4*)&Pt[wave][(16 + l15) * 136 + colt * 16 + quad * 4] = ph1;
    }

    // O^T += V^T P^T : vf straight from global (L2-resident), shared across t
#pragma unroll
    for (int ks = 0; ks < 4; ++ks) {
      f16x8 pf0 = *(const f16x8*)&Pt[wave][(l15) * 136 + ks * 32 + quad * 8];
      f16x8 pf1 = *(const f16x8*)&Pt[wave][(16 + l15) * 136 + ks * 32 + quad * 8];
#pragma unroll
      for (int c = 0; c < 4; ++c) {
        f16x8 vf = *(const f16x8*)&Vh[(size_t)(c * 16 + l15) * kS + kb + ks * 32 + quad * 8];
        o_acc[0][c] = MFMA_16x16x32(vf, pf0, o_acc[0][c]);
        o_acc[1][c] = MFMA_16x16x32(vf, pf1, o_acc[1][c]);
      }
    }
  }

  // epilogue: l(q) = reduce over quads; O^T lane holds 4 consecutive d for q=l15
  const int h = bh & 15;
#pragma unroll
  for (int t = 0; t < 2; ++t) {
    float lsum = l_part[t];
    lsum += __shfl_xor(lsum, 16, 64);
    lsum += __shfl_xor(lsum, 32, 64);
    float inv = 1.0f / lsum;
    int q = q0 + wave * 32 + t * 16 + l15;
#pragma unroll
    for (int c = 0; c < 4; ++c) {
      f16x4 oh;
#pragma unroll
      for (int r = 0; r < 4; ++r) oh[r] = (_Float16)(o_acc[t][c][r] * inv);
      *(f16x4*)&ctx[((size_t)(b * kS + q)) * kDim + h * kD + c * 16 + quad * 4] = oh;
    }
  }
}

// ------------- output GEMM (BK=64, double-buffered LDS, 1 barrier/iter) -------------
__global__ __launch_bounds__(256, 2) void gemm_out(
    const _Float16* __restrict__ A, const _Float16* __restrict__ Bt,
    const float* __restrict__ bias, float* __restrict__ out) {
  __shared__ alignas(16) _Float16 As[2][128 * 72];
  __shared__ alignas(16) _Float16 Bs[2][128 * 72];
  const int tid = threadIdx.x;
  const int lane = tid & 63;
  const int wave = tid >> 6;
  const int wm = wave & 1, wn = wave >> 1;
  const int l15 = lane & 15, quad = lane >> 4;
  const int m0 = blockIdx.x * 128, n0 = blockIdx.y * 128;

  const int srow = tid >> 3;
  const int skc = (tid & 7) * 8;

  f32x4 acc[4][4] = {};
  f16x8 ra[4], rb[4];

#pragma unroll
  for (int i = 0; i < 4; ++i) {
    int row = srow + 32 * i;
    ra[i] = *(const f16x8*)&A[(size_t)(m0 + row) * kDim + skc];
    rb[i] = *(const f16x8*)&Bt[(size_t)(n0 + row) * kDim + skc];
  }
#pragma unroll
  for (int i = 0; i < 4; ++i) {
    int row = srow + 32 * i;
    *(f16x8*)&As[0][row * 72 + skc] = ra[i];
    *(f16x8*)&Bs[0][row * 72 + skc] = rb[i];
  }

  for (int kt = 0; kt < 16; ++kt) {
    const int cur = kt & 1;
    if (kt + 1 < 16) {
      int k0 = (kt + 1) * 64;
#pragma unroll
      for (int i = 0; i < 4; ++i) {
        int row = srow + 32 * i;
        ra[i] = *(const f16x8*)&A[(size_t)(m0 + row) * kDim + k0 + skc];
        rb[i] = *(const f16x8*)&Bt[(size_t)(n0 + row) * kDim + k0 + skc];
      }
    }
    wg_barrier_lds();
#pragma unroll
    for (int kk = 0; kk < 2; ++kk) {
      f16x8 af[4], bf[4];
#pragma unroll
      for (int t = 0; t < 4; ++t) af[t] = *(const f16x8*)&As[cur][(wm * 64 + t * 16 + l15) * 72 + kk * 32 + quad * 8];
#pragma unroll
      for (int t = 0; t < 4; ++t) bf[t] = *(const f16x8*)&Bs[cur][(wn * 64 + t * 16 + l15) * 72 + kk * 32 + quad * 8];
#pragma unroll
      for (int i = 0; i < 4; ++i)
#pragma unroll
        for (int j = 0; j < 4; ++j)
          acc[i][j] = MFMA_16x16x32(af[i], bf[j], acc[i][j]);
    }
    if (kt + 1 < 16) {
#pragma unroll
      for (int i = 0; i < 4; ++i) {
        int row = srow + 32 * i;
        *(f16x8*)&As[cur ^ 1][row * 72 + skc] = ra[i];
        *(f16x8*)&Bs[cur ^ 1][row * 72 + skc] = rb[i];
      }
    }
  }

  const int mbase = m0 + wm * 64 + quad * 4;
  const int nbase = n0 + wn * 64 + l15;
#pragma unroll
  for (int j = 0; j < 4; ++j) {
    int n = nbase + j * 16;
    float bv = bias[n];
#pragma unroll
    for (int i = 0; i < 4; ++i) {
      int mrow = mbase + i * 16;
#pragma unroll
      for (int r = 0; r < 4; ++r)
        out[(size_t)(mrow + r) * kDim + n] = acc[i][j][r] + bv;
    }
  }
}

extern "C" void kernel_launch(void* const* d_in, const int* in_sizes, int n_in,
                              void* d_out, int out_size, void* d_ws, size_t ws_size,
                              hipStream_t stream) {
  (void)in_sizes; (void)n_in; (void)out_size; (void)ws_size;
  const float* X    = (const float*)d_in[0];
  const float* mask = (const float*)d_in[1];
  const float* Wq   = (const float*)d_in[2];
  const float* bq   = (const float*)d_in[3];
  const float* Wk   = (const float*)d_in[4];
  const float* bk   = (const float*)d_in[5];
  const float* Wv   = (const float*)d_in[6];
  const float* bv   = (const float*)d_in[7];
  const float* Wo   = (const float*)d_in[8];
  const float* bo   = (const float*)d_in[9];
  float* out = (float*)d_out;

  char* ws = (char*)d_ws;
  _Float16* Xh   = (_Float16*)(ws);                        // 8 MB
  _Float16* Wqt  = (_Float16*)(ws + ((size_t)8  << 20));   // 2 MB each
  _Float16* Wkt  = (_Float16*)(ws + ((size_t)10 << 20));
  _Float16* Wvt  = (_Float16*)(ws + ((size_t)12 << 20));
  _Float16* Wot  = (_Float16*)(ws + ((size_t)14 << 20));
  _Float16* Qh   = (_Float16*)(ws + ((size_t)16 << 20));   // 8 MB each
  _Float16* Kh   = (_Float16*)(ws + ((size_t)24 << 20));
  _Float16* Vh   = (_Float16*)(ws + ((size_t)32 << 20));   // [B][H][D][S]
  _Float16* Ch   = (_Float16*)(ws + ((size_t)40 << 20));   // 8 MB

  cvt_f32_to_f16<<<dim3(kM * kDim / 8 / 256), dim3(256), 0, stream>>>(X, Xh, kM * kDim / 8);
  transpose_cvt_w<<<dim3(16, 16, 4), dim3(256), 0, stream>>>(Wq, Wk, Wv, Wo, Wqt, Wkt, Wvt, Wot);
  gemm_qkv<<<dim3(32, 8, 3), dim3(256), 0, stream>>>(Xh, Wqt, Wkt, Wvt, bq, bk, bv, Qh, Kh, Vh);
  attn<<<dim3(512), dim3(256), 0, stream>>>(Qh, Kh, Vh, mask, Ch);
  gemm_out<<<dim3(32, 8), dim3(256), 0, stream>>>(Ch, Wot, bo, out);
}

// Round 3
// 227.535 us; speedup vs baseline: 1.1750x; 1.1750x over previous
//
#include <hip/hip_runtime.h>
#include <cstdint>
#include <cstddef>

typedef __attribute__((ext_vector_type(8))) _Float16 f16x8;
typedef __attribute__((ext_vector_type(4))) _Float16 f16x4;
typedef __attribute__((ext_vector_type(4))) float f32x4;

#define MFMA_16x16x32(a, b, c) __builtin_amdgcn_mfma_f32_16x16x32_f16((a), (b), (c), 0, 0, 0)

static constexpr int kB = 2, kS = 2048, kDim = 1024, kH = 16, kD = 64;
static constexpr int kM = kB * kS;  // 4096 rows total
// 1/sqrt(64) * log2(e), folded into Q at projection time
static constexpr float kQScale = 0.125f * 1.44269504088896340736f;
// -1e6 * log2(e): mask penalty in exp2 domain
static constexpr float kPenC = 1.44269504088896340736e6f;

// Raw workgroup barrier: drain only LDS ops (lgkmcnt), NOT vmcnt, so register
// prefetch loads stay in flight across the barrier.
__device__ __forceinline__ void wg_barrier_lds() {
  asm volatile("s_waitcnt lgkmcnt(0)" ::: "memory");
  __builtin_amdgcn_s_barrier();
}

// ---------------- elementwise f32 -> f16 ----------------
__global__ void cvt_f32_to_f16(const float* __restrict__ in, _Float16* __restrict__ out, int n8) {
  int i = blockIdx.x * blockDim.x + threadIdx.x;
  if (i >= n8) return;
  const float4* p = (const float4*)in + (size_t)i * 2;
  float4 a = p[0], b = p[1];
  f16x8 h;
  h[0] = (_Float16)a.x; h[1] = (_Float16)a.y; h[2] = (_Float16)a.z; h[3] = (_Float16)a.w;
  h[4] = (_Float16)b.x; h[5] = (_Float16)b.y; h[6] = (_Float16)b.z; h[7] = (_Float16)b.w;
  ((f16x8*)out)[i] = h;
}

// ------------- W [K][N] f32  ->  Wt [N][K] f16 (4 matrices) -------------
__global__ void transpose_cvt_w(const float* __restrict__ w0, const float* __restrict__ w1,
                                const float* __restrict__ w2, const float* __restrict__ w3,
                                _Float16* __restrict__ o0, _Float16* __restrict__ o1,
                                _Float16* __restrict__ o2, _Float16* __restrict__ o3) {
  const float* w; _Float16* o;
  switch (blockIdx.z) {
    case 0: w = w0; o = o0; break;
    case 1: w = w1; o = o1; break;
    case 2: w = w2; o = o2; break;
    default: w = w3; o = o3; break;
  }
  __shared__ alignas(16) _Float16 tile[64][72];
  const int kt = blockIdx.x * 64;
  const int nt = blockIdx.y * 64;
  const int tr = threadIdx.x >> 4;
  const int tc = threadIdx.x & 15;
#pragma unroll
  for (int rr = 0; rr < 4; ++rr) {
    int r = rr * 16 + tr;
    float4 v = *(const float4*)&w[(size_t)(kt + r) * kDim + nt + tc * 4];
    f16x4 hv;
    hv[0] = (_Float16)v.x; hv[1] = (_Float16)v.y; hv[2] = (_Float16)v.z; hv[3] = (_Float16)v.w;
    *(f16x4*)&tile[r][tc * 4] = hv;
  }
  __syncthreads();
#pragma unroll
  for (int rr = 0; rr < 4; ++rr) {
    int nl = rr * 16 + tr;
    f16x4 hv;
    hv[0] = tile[tc * 4 + 0][nl];
    hv[1] = tile[tc * 4 + 1][nl];
    hv[2] = tile[tc * 4 + 2][nl];
    hv[3] = tile[tc * 4 + 3][nl];
    *(f16x4*)&o[(size_t)(nt + nl) * kDim + kt + tc * 4] = hv;
  }
}

// ------------- QKV projection GEMM (BK=64, double-buffered LDS, 1 barrier/iter) -------------
__global__ __launch_bounds__(256, 2) void gemm_qkv(
    const _Float16* __restrict__ A,
    const _Float16* __restrict__ wt0, const _Float16* __restrict__ wt1, const _Float16* __restrict__ wt2,
    const float* __restrict__ bias0, const float* __restrict__ bias1, const float* __restrict__ bias2,
    _Float16* __restrict__ oq, _Float16* __restrict__ ok, _Float16* __restrict__ ov) {
  const _Float16* Bt; const float* bias; _Float16* out;
  switch (blockIdx.z) {
    case 0: Bt = wt0; bias = bias0; out = oq; break;
    case 1: Bt = wt1; bias = bias1; out = ok; break;
    default: Bt = wt2; bias = bias2; out = ov; break;
  }
  __shared__ alignas(16) _Float16 As[2][128 * 72];
  __shared__ alignas(16) _Float16 Bs[2][128 * 72];
  const int tid = threadIdx.x;
  const int lane = tid & 63;
  const int wave = tid >> 6;
  const int wm = wave & 1, wn = wave >> 1;
  const int l15 = lane & 15, quad = lane >> 4;
  const int m0 = blockIdx.x * 128, n0 = blockIdx.y * 128;

  const int srow = tid >> 3;             // staging row (tid + 256*i -> row = srow + 32*i)
  const int skc = (tid & 7) * 8;         // staging k-offset

  f32x4 acc[4][4] = {};
  f16x8 ra[4], rb[4];

  // prologue: stage k0=0 into buffer 0
#pragma unroll
  for (int i = 0; i < 4; ++i) {
    int row = srow + 32 * i;
    ra[i] = *(const f16x8*)&A[(size_t)(m0 + row) * kDim + skc];
    rb[i] = *(const f16x8*)&Bt[(size_t)(n0 + row) * kDim + skc];
  }
#pragma unroll
  for (int i = 0; i < 4; ++i) {
    int row = srow + 32 * i;
    *(f16x8*)&As[0][row * 72 + skc] = ra[i];
    *(f16x8*)&Bs[0][row * 72 + skc] = rb[i];
  }

  for (int kt = 0; kt < 16; ++kt) {
    const int cur = kt & 1;
    if (kt + 1 < 16) {
      int k0 = (kt + 1) * 64;
#pragma unroll
      for (int i = 0; i < 4; ++i) {
        int row = srow + 32 * i;
        ra[i] = *(const f16x8*)&A[(size_t)(m0 + row) * kDim + k0 + skc];
        rb[i] = *(const f16x8*)&Bt[(size_t)(n0 + row) * kDim + k0 + skc];
      }
    }
    wg_barrier_lds();  // writes to buffer `cur` (prev iter / prologue) complete
#pragma unroll
    for (int kk = 0; kk < 2; ++kk) {
      f16x8 af[4], bf[4];
#pragma unroll
      for (int t = 0; t < 4; ++t) af[t] = *(const f16x8*)&As[cur][(wm * 64 + t * 16 + l15) * 72 + kk * 32 + quad * 8];
#pragma unroll
      for (int t = 0; t < 4; ++t) bf[t] = *(const f16x8*)&Bs[cur][(wn * 64 + t * 16 + l15) * 72 + kk * 32 + quad * 8];
#pragma unroll
      for (int i = 0; i < 4; ++i)
#pragma unroll
        for (int j = 0; j < 4; ++j)
          acc[i][j] = MFMA_16x16x32(af[i], bf[j], acc[i][j]);
    }
    if (kt + 1 < 16) {
#pragma unroll
      for (int i = 0; i < 4; ++i) {
        int row = srow + 32 * i;
        *(f16x8*)&As[cur ^ 1][row * 72 + skc] = ra[i];
        *(f16x8*)&Bs[cur ^ 1][row * 72 + skc] = rb[i];
      }
    }
  }

  const int mbase = m0 + wm * 64 + quad * 4;
  const int nbase = n0 + wn * 64 + l15;
  if (blockIdx.z == 2) {
#pragma unroll
    for (int j = 0; j < 4; ++j) {
      int n = nbase + j * 16;
      float bv = bias[n];
      int h = n >> 6, d = n & 63;
#pragma unroll
      for (int i = 0; i < 4; ++i) {
        int m = mbase + i * 16;
        int b = m >> 11, s = m & (kS - 1);
        f16x4 hv;
#pragma unroll
        for (int r = 0; r < 4; ++r) hv[r] = (_Float16)(acc[i][j][r] + bv);
        *(f16x4*)&out[((size_t)((b * kH + h) * kD + d)) * kS + s] = hv;
      }
    }
  } else {
    const float osc = (blockIdx.z == 0) ? kQScale : 1.0f;
#pragma unroll
    for (int j = 0; j < 4; ++j) {
      int n = nbase + j * 16;
      float bv = bias[n];
      int h = n >> 6, d = n & 63;
#pragma unroll
      for (int i = 0; i < 4; ++i) {
        int mrow = mbase + i * 16;
#pragma unroll
        for (int r = 0; r < 4; ++r) {
          int m = mrow + r;
          int b = m >> 11, s = m & (kS - 1);
          out[(size_t)(((b * kH + h) * kS) + s) * kD + d] = (_Float16)((acc[i][j][r] + bv) * osc);
        }
      }
    }
  }
}

// ------------- flash attention, S^T formulation, v3 -------------
// vs R4-75.4us baseline:
//  - Vs RESTORED to LDS (R1's direct-global V was latency-bound at 2 waves/SIMD)
//  - Pt and Vs: stride 256B + byte-XOR swizzle ((row&7)<<4) -> kills the 8-way
//    "lanes read different rows at same col" bank conflicts (m214 recipe)
//  - K AND V tiles register-prefetched one iter ahead; lgkm-only barriers so
//    the prefetch stays in flight under compute
//  - full mask-penalty row staged to LDS once (no per-iter vmem in compute
//    phase -> vmcnt never forced to drain the prefetch)
//  - XCD-bijective swizzle: each XCD owns 4 consecutive bh (2MB K/V <= 4MB L2)
__global__ __launch_bounds__(256, 2) void attn(
    const _Float16* __restrict__ Q, const _Float16* __restrict__ K,
    const _Float16* __restrict__ V, const float* __restrict__ mask,
    _Float16* __restrict__ ctx) {
  const int id = blockIdx.x;
  const int logical = (id & 7) * 64 + (id >> 3);
  const int bh = logical >> 4;    // 0..31
  const int qblk = logical & 15;  // 0..15
  const int b = bh >> 4;
  const int q0 = qblk * 128;
  const int tid = threadIdx.x, lane = tid & 63, wave = tid >> 6;
  const int l15 = lane & 15, quad = lane >> 4;

  __shared__ alignas(16) _Float16 Ks[128 * 72];     // [key][d], stride 144B (~2-way, free)
  __shared__ alignas(16) _Float16 Vs[64 * 128];     // [d][key], 256B stride, XOR-swizzled
  __shared__ alignas(16) _Float16 Pt[4][32 * 128];  // per-wave P^T [q][key], XOR-swizzled
  __shared__ alignas(16) float pens[kS];            // (mask-1)*kPenC for all keys

  const _Float16* Qh = Q + (size_t)bh * kS * kD;
  const _Float16* Kh = K + (size_t)bh * kS * kD;
  const _Float16* Vh = V + (size_t)bh * kS * kD;  // [d][s]

  // mask penalties for the whole row, staged once (8KB)
#pragma unroll
  for (int i = 0; i < 2; ++i) {
    float4 mv4 = *(const float4*)&mask[(size_t)b * kS + tid * 8 + i * 4];
    float4 pv;
    pv.x = (mv4.x - 1.0f) * kPenC;
    pv.y = (mv4.y - 1.0f) * kPenC;
    pv.z = (mv4.z - 1.0f) * kPenC;
    pv.w = (mv4.w - 1.0f) * kPenC;
    *(float4*)&pens[tid * 8 + i * 4] = pv;
  }

  f16x8 qf[2][2];
#pragma unroll
  for (int t = 0; t < 2; ++t) {
    int qrow = q0 + wave * 32 + t * 16 + l15;
#pragma unroll
    for (int kk = 0; kk < 2; ++kk)
      qf[t][kk] = *(const f16x8*)&Qh[(size_t)qrow * kD + kk * 32 + quad * 8];
  }

  f32x4 o_acc[2][4] = {};   // O^T: [t][d-tile], C-layout (row=d, col=q)
  float l_part[2] = {0.0f, 0.0f};

  const int srow = tid >> 3;       // K staging row base
  const int skc = (tid & 7) * 8;   // K staging d-offset (f16)
  const int vrow = tid >> 4;       // V staging row base (c = tid+256i -> row = vrow+16i)
  const int vcol16 = (tid & 15) * 16;  // V staging byte offset within row
  char* PtW = (char*)&Pt[wave][0];
  const int xr = (l15 & 7) << 4;   // XOR term for this lane's Pt/Vs row

  // prologue: prefetch first K/V tiles into registers
  f16x8 kreg[4], vreg[4];
#pragma unroll
  for (int i = 0; i < 4; ++i)
    kreg[i] = *(const f16x8*)&Kh[(size_t)(srow + 32 * i) * kD + skc];
#pragma unroll
  for (int i = 0; i < 4; ++i)
    vreg[i] = *(const f16x8*)&Vh[(size_t)(vrow + 16 * i) * kS + (tid & 15) * 8];

  for (int it = 0; it < 16; ++it) {
    const int kb = it * 128;
    wg_barrier_lds();   // all waves done reading Ks/Vs from previous iter
#pragma unroll
    for (int i = 0; i < 4; ++i)
      *(f16x8*)&Ks[(srow + 32 * i) * 72 + skc] = kreg[i];
#pragma unroll
    for (int i = 0; i < 4; ++i) {
      int row = vrow + 16 * i;
      *(f16x8*)((char*)Vs + row * 256 + (vcol16 ^ ((row & 7) << 4))) = vreg[i];
    }
    if (it + 1 < 16) {  // issue next K/V tiles; fly under compute (no vmcnt drain)
#pragma unroll
      for (int i = 0; i < 4; ++i)
        kreg[i] = *(const f16x8*)&Kh[(size_t)(kb + 128 + srow + 32 * i) * kD + skc];
#pragma unroll
      for (int i = 0; i < 4; ++i)
        vreg[i] = *(const f16x8*)&Vh[(size_t)(vrow + 16 * i) * kS + kb + 128 + (tid & 15) * 8];
    }
    wg_barrier_lds();   // Ks/Vs ready

    // S^T = K Q^T per 16-key column-tile; exp2 with mask penalty; swizzled Pt store
#pragma unroll
    for (int colt = 0; colt < 8; ++colt) {
      f16x8 kf0 = *(const f16x8*)&Ks[(colt * 16 + l15) * 72 + quad * 8];
      f16x8 kf1 = *(const f16x8*)&Ks[(colt * 16 + l15) * 72 + 32 + quad * 8];
      f32x4 s0 = {}, s1 = {};
      s0 = MFMA_16x16x32(kf0, qf[0][0], s0);
      s0 = MFMA_16x16x32(kf1, qf[0][1], s0);
      s1 = MFMA_16x16x32(kf0, qf[1][0], s1);
      s1 = MFMA_16x16x32(kf1, qf[1][1], s1);
      f32x4 pn = *(const f32x4*)&pens[kb + colt * 16 + quad * 4];
      f16x4 ph0, ph1;
#pragma unroll
      for (int r = 0; r < 4; ++r) {
        float p0 = __builtin_exp2f(s0[r] + pn[r]);
        float p1 = __builtin_exp2f(s1[r] + pn[r]);
        l_part[0] += p0;
        l_part[1] += p1;
        ph0[r] = (_Float16)p0;
        ph1[r] = (_Float16)p1;
      }
      int bw = colt * 32 + quad * 8;
      *(f16x4*)(PtW + l15 * 256 + (bw ^ xr)) = ph0;
      *(f16x4*)(PtW + (16 + l15) * 256 + (bw ^ xr)) = ph1;
    }

    // O^T += V^T P^T (all LDS reads swizzle-matched, conflict-free-ish)
#pragma unroll
    for (int ks = 0; ks < 4; ++ks) {
      int br = ks * 64 + quad * 16;
      f16x8 pf0 = *(const f16x8*)(PtW + l15 * 256 + (br ^ xr));
      f16x8 pf1 = *(const f16x8*)(PtW + (16 + l15) * 256 + (br ^ xr));
#pragma unroll
      for (int ct = 0; ct < 4; ++ct) {
        int row = ct * 16 + l15;
        f16x8 vf = *(const f16x8*)((char*)Vs + row * 256 + (br ^ xr));
        o_acc[0][ct] = MFMA_16x16x32(vf, pf0, o_acc[0][ct]);
        o_acc[1][ct] = MFMA_16x16x32(vf, pf1, o_acc[1][ct]);
      }
    }
  }

  // epilogue: l(q) = reduce over quads; O^T lane holds 4 consecutive d for q=l15
  const int h = bh & 15;
#pragma unroll
  for (int t = 0; t < 2; ++t) {
    float lsum = l_part[t];
    lsum += __shfl_xor(lsum, 16, 64);
    lsum += __shfl_xor(lsum, 32, 64);
    float inv = 1.0f / lsum;
    int q = q0 + wave * 32 + t * 16 + l15;
#pragma unroll
    for (int c = 0; c < 4; ++c) {
      f16x4 oh;
#pragma unroll
      for (int r = 0; r < 4; ++r) oh[r] = (_Float16)(o_acc[t][c][r] * inv);
      *(f16x4*)&ctx[((size_t)(b * kS + q)) * kDim + h * kD + c * 16 + quad * 4] = oh;
    }
  }
}

// ------------- output GEMM (BK=64, double-buffered LDS, 1 barrier/iter) -------------
__global__ __launch_bounds__(256, 2) void gemm_out(
    const _Float16* __restrict__ A, const _Float16* __restrict__ Bt,
    const float* __restrict__ bias, float* __restrict__ out) {
  __shared__ alignas(16) _Float16 As[2][128 * 72];
  __shared__ alignas(16) _Float16 Bs[2][128 * 72];
  const int tid = threadIdx.x;
  const int lane = tid & 63;
  const int wave = tid >> 6;
  const int wm = wave & 1, wn = wave >> 1;
  const int l15 = lane & 15, quad = lane >> 4;
  const int m0 = blockIdx.x * 128, n0 = blockIdx.y * 128;

  const int srow = tid >> 3;
  const int skc = (tid & 7) * 8;

  f32x4 acc[4][4] = {};
  f16x8 ra[4], rb[4];

#pragma unroll
  for (int i = 0; i < 4; ++i) {
    int row = srow + 32 * i;
    ra[i] = *(const f16x8*)&A[(size_t)(m0 + row) * kDim + skc];
    rb[i] = *(const f16x8*)&Bt[(size_t)(n0 + row) * kDim + skc];
  }
#pragma unroll
  for (int i = 0; i < 4; ++i) {
    int row = srow + 32 * i;
    *(f16x8*)&As[0][row * 72 + skc] = ra[i];
    *(f16x8*)&Bs[0][row * 72 + skc] = rb[i];
  }

  for (int kt = 0; kt < 16; ++kt) {
    const int cur = kt & 1;
    if (kt + 1 < 16) {
      int k0 = (kt + 1) * 64;
#pragma unroll
      for (int i = 0; i < 4; ++i) {
        int row = srow + 32 * i;
        ra[i] = *(const f16x8*)&A[(size_t)(m0 + row) * kDim + k0 + skc];
        rb[i] = *(const f16x8*)&Bt[(size_t)(n0 + row) * kDim + k0 + skc];
      }
    }
    wg_barrier_lds();
#pragma unroll
    for (int kk = 0; kk < 2; ++kk) {
      f16x8 af[4], bf[4];
#pragma unroll
      for (int t = 0; t < 4; ++t) af[t] = *(const f16x8*)&As[cur][(wm * 64 + t * 16 + l15) * 72 + kk * 32 + quad * 8];
#pragma unroll
      for (int t = 0; t < 4; ++t) bf[t] = *(const f16x8*)&Bs[cur][(wn * 64 + t * 16 + l15) * 72 + kk * 32 + quad * 8];
#pragma unroll
      for (int i = 0; i < 4; ++i)
#pragma unroll
        for (int j = 0; j < 4; ++j)
          acc[i][j] = MFMA_16x16x32(af[i], bf[j], acc[i][j]);
    }
    if (kt + 1 < 16) {
#pragma unroll
      for (int i = 0; i < 4; ++i) {
        int row = srow + 32 * i;
        *(f16x8*)&As[cur ^ 1][row * 72 + skc] = ra[i];
        *(f16x8*)&Bs[cur ^ 1][row * 72 + skc] = rb[i];
      }
    }
  }

  const int mbase = m0 + wm * 64 + quad * 4;
  const int nbase = n0 + wn * 64 + l15;
#pragma unroll
  for (int j = 0; j < 4; ++j) {
    int n = nbase + j * 16;
    float bv = bias[n];
#pragma unroll
    for (int i = 0; i < 4; ++i) {
      int mrow = mbase + i * 16;
#pragma unroll
      for (int r = 0; r < 4; ++r)
        out[(size_t)(mrow + r) * kDim + n] = acc[i][j][r] + bv;
    }
  }
}

extern "C" void kernel_launch(void* const* d_in, const int* in_sizes, int n_in,
                              void* d_out, int out_size, void* d_ws, size_t ws_size,
                              hipStream_t stream) {
  (void)in_sizes; (void)n_in; (void)out_size; (void)ws_size;
  const float* X    = (const float*)d_in[0];
  const float* mask = (const float*)d_in[1];
  const float* Wq   = (const float*)d_in[2];
  const float* bq   = (const float*)d_in[3];
  const float* Wk   = (const float*)d_in[4];
  const float* bk   = (const float*)d_in[5];
  const float* Wv   = (const float*)d_in[6];
  const float* bv   = (const float*)d_in[7];
  const float* Wo   = (const float*)d_in[8];
  const float* bo   = (const float*)d_in[9];
  float* out = (float*)d_out;

  char* ws = (char*)d_ws;
  _Float16* Xh   = (_Float16*)(ws);                        // 8 MB
  _Float16* Wqt  = (_Float16*)(ws + ((size_t)8  << 20));   // 2 MB each
  _Float16* Wkt  = (_Float16*)(ws + ((size_t)10 << 20));
  _Float16* Wvt  = (_Float16*)(ws + ((size_t)12 << 20));
  _Float16* Wot  = (_Float16*)(ws + ((size_t)14 << 20));
  _Float16* Qh   = (_Float16*)(ws + ((size_t)16 << 20));   // 8 MB each
  _Float16* Kh   = (_Float16*)(ws + ((size_t)24 << 20));
  _Float16* Vh   = (_Float16*)(ws + ((size_t)32 << 20));   // [B][H][D][S]
  _Float16* Ch   = (_Float16*)(ws + ((size_t)40 << 20));   // 8 MB

  cvt_f32_to_f16<<<dim3(kM * kDim / 8 / 256), dim3(256), 0, stream>>>(X, Xh, kM * kDim / 8);
  transpose_cvt_w<<<dim3(16, 16, 4), dim3(256), 0, stream>>>(Wq, Wk, Wv, Wo, Wqt, Wkt, Wvt, Wot);
  gemm_qkv<<<dim3(32, 8, 3), dim3(256), 0, stream>>>(Xh, Wqt, Wkt, Wvt, bq, bk, bv, Qh, Kh, Vh);
  attn<<<dim3(512), dim3(256), 0, stream>>>(Qh, Kh, Vh, mask, Ch);
  gemm_out<<<dim3(32, 8), dim3(256), 0, stream>>>(Ch, Wot, bo, out);
}

// Round 4
// 209.539 us; speedup vs baseline: 1.2759x; 1.0859x over previous
//
#include <hip/hip_runtime.h>
#include <cstdint>
#include <cstddef>

typedef __attribute__((ext_vector_type(8))) _Float16 f16x8;
typedef __attribute__((ext_vector_type(4))) _Float16 f16x4;
typedef __attribute__((ext_vector_type(4))) float f32x4;

#define MFMA_16x16x32(a, b, c) __builtin_amdgcn_mfma_f32_16x16x32_f16((a), (b), (c), 0, 0, 0)

static constexpr int kB = 2, kS = 2048, kDim = 1024, kH = 16, kD = 64;
static constexpr int kM = kB * kS;  // 4096 rows total
// 1/sqrt(64) * log2(e), folded into Q at projection time
static constexpr float kQScale = 0.125f * 1.44269504088896340736f;
// -1e6 * log2(e): mask penalty in exp2 domain
static constexpr float kPenC = 1.44269504088896340736e6f;

// Raw workgroup barrier: drain only LDS ops (lgkmcnt), NOT vmcnt, so register
// prefetch loads stay in flight across the barrier.
__device__ __forceinline__ void wg_barrier_lds() {
  asm volatile("s_waitcnt lgkmcnt(0)" ::: "memory");
  __builtin_amdgcn_s_barrier();
}

// ---------------- elementwise f32 -> f16 ----------------
__global__ void cvt_f32_to_f16(const float* __restrict__ in, _Float16* __restrict__ out, int n8) {
  int i = blockIdx.x * blockDim.x + threadIdx.x;
  if (i >= n8) return;
  const float4* p = (const float4*)in + (size_t)i * 2;
  float4 a = p[0], b = p[1];
  f16x8 h;
  h[0] = (_Float16)a.x; h[1] = (_Float16)a.y; h[2] = (_Float16)a.z; h[3] = (_Float16)a.w;
  h[4] = (_Float16)b.x; h[5] = (_Float16)b.y; h[6] = (_Float16)b.z; h[7] = (_Float16)b.w;
  ((f16x8*)out)[i] = h;
}

// ------------- W [K][N] f32  ->  Wt [N][K] f16 (4 matrices) -------------
__global__ void transpose_cvt_w(const float* __restrict__ w0, const float* __restrict__ w1,
                                const float* __restrict__ w2, const float* __restrict__ w3,
                                _Float16* __restrict__ o0, _Float16* __restrict__ o1,
                                _Float16* __restrict__ o2, _Float16* __restrict__ o3) {
  const float* w; _Float16* o;
  switch (blockIdx.z) {
    case 0: w = w0; o = o0; break;
    case 1: w = w1; o = o1; break;
    case 2: w = w2; o = o2; break;
    default: w = w3; o = o3; break;
  }
  __shared__ alignas(16) _Float16 tile[64][72];
  const int kt = blockIdx.x * 64;
  const int nt = blockIdx.y * 64;
  const int tr = threadIdx.x >> 4;
  const int tc = threadIdx.x & 15;
#pragma unroll
  for (int rr = 0; rr < 4; ++rr) {
    int r = rr * 16 + tr;
    float4 v = *(const float4*)&w[(size_t)(kt + r) * kDim + nt + tc * 4];
    f16x4 hv;
    hv[0] = (_Float16)v.x; hv[1] = (_Float16)v.y; hv[2] = (_Float16)v.z; hv[3] = (_Float16)v.w;
    *(f16x4*)&tile[r][tc * 4] = hv;
  }
  __syncthreads();
#pragma unroll
  for (int rr = 0; rr < 4; ++rr) {
    int nl = rr * 16 + tr;
    f16x4 hv;
    hv[0] = tile[tc * 4 + 0][nl];
    hv[1] = tile[tc * 4 + 1][nl];
    hv[2] = tile[tc * 4 + 2][nl];
    hv[3] = tile[tc * 4 + 3][nl];
    *(f16x4*)&o[(size_t)(nt + nl) * kDim + kt + tc * 4] = hv;
  }
}

// ------------- QKV projection GEMM (BK=64, double-buffered LDS, 1 barrier/iter) -------------
__global__ __launch_bounds__(256, 2) void gemm_qkv(
    const _Float16* __restrict__ A,
    const _Float16* __restrict__ wt0, const _Float16* __restrict__ wt1, const _Float16* __restrict__ wt2,
    const float* __restrict__ bias0, const float* __restrict__ bias1, const float* __restrict__ bias2,
    _Float16* __restrict__ oq, _Float16* __restrict__ ok, _Float16* __restrict__ ov) {
  const _Float16* Bt; const float* bias; _Float16* out;
  switch (blockIdx.z) {
    case 0: Bt = wt0; bias = bias0; out = oq; break;
    case 1: Bt = wt1; bias = bias1; out = ok; break;
    default: Bt = wt2; bias = bias2; out = ov; break;
  }
  __shared__ alignas(16) _Float16 As[2][128 * 72];
  __shared__ alignas(16) _Float16 Bs[2][128 * 72];
  const int tid = threadIdx.x;
  const int lane = tid & 63;
  const int wave = tid >> 6;
  const int wm = wave & 1, wn = wave >> 1;
  const int l15 = lane & 15, quad = lane >> 4;
  const int m0 = blockIdx.x * 128, n0 = blockIdx.y * 128;

  const int srow = tid >> 3;             // staging row (tid + 256*i -> row = srow + 32*i)
  const int skc = (tid & 7) * 8;         // staging k-offset

  f32x4 acc[4][4] = {};
  f16x8 ra[4], rb[4];

  // prologue: stage k0=0 into buffer 0
#pragma unroll
  for (int i = 0; i < 4; ++i) {
    int row = srow + 32 * i;
    ra[i] = *(const f16x8*)&A[(size_t)(m0 + row) * kDim + skc];
    rb[i] = *(const f16x8*)&Bt[(size_t)(n0 + row) * kDim + skc];
  }
#pragma unroll
  for (int i = 0; i < 4; ++i) {
    int row = srow + 32 * i;
    *(f16x8*)&As[0][row * 72 + skc] = ra[i];
    *(f16x8*)&Bs[0][row * 72 + skc] = rb[i];
  }

  for (int kt = 0; kt < 16; ++kt) {
    const int cur = kt & 1;
    if (kt + 1 < 16) {
      int k0 = (kt + 1) * 64;
#pragma unroll
      for (int i = 0; i < 4; ++i) {
        int row = srow + 32 * i;
        ra[i] = *(const f16x8*)&A[(size_t)(m0 + row) * kDim + k0 + skc];
        rb[i] = *(const f16x8*)&Bt[(size_t)(n0 + row) * kDim + k0 + skc];
      }
    }
    wg_barrier_lds();  // writes to buffer `cur` (prev iter / prologue) complete
#pragma unroll
    for (int kk = 0; kk < 2; ++kk) {
      f16x8 af[4], bf[4];
#pragma unroll
      for (int t = 0; t < 4; ++t) af[t] = *(const f16x8*)&As[cur][(wm * 64 + t * 16 + l15) * 72 + kk * 32 + quad * 8];
#pragma unroll
      for (int t = 0; t < 4; ++t) bf[t] = *(const f16x8*)&Bs[cur][(wn * 64 + t * 16 + l15) * 72 + kk * 32 + quad * 8];
      __builtin_amdgcn_s_setprio(1);
#pragma unroll
      for (int i = 0; i < 4; ++i)
#pragma unroll
        for (int j = 0; j < 4; ++j)
          acc[i][j] = MFMA_16x16x32(af[i], bf[j], acc[i][j]);
      __builtin_amdgcn_s_setprio(0);
    }
    if (kt + 1 < 16) {
#pragma unroll
      for (int i = 0; i < 4; ++i) {
        int row = srow + 32 * i;
        *(f16x8*)&As[cur ^ 1][row * 72 + skc] = ra[i];
        *(f16x8*)&Bs[cur ^ 1][row * 72 + skc] = rb[i];
      }
    }
  }

  const int mbase = m0 + wm * 64 + quad * 4;
  const int nbase = n0 + wn * 64 + l15;
  if (blockIdx.z == 2) {
#pragma unroll
    for (int j = 0; j < 4; ++j) {
      int n = nbase + j * 16;
      float bv = bias[n];
      int h = n >> 6, d = n & 63;
#pragma unroll
      for (int i = 0; i < 4; ++i) {
        int m = mbase + i * 16;
        int b = m >> 11, s = m & (kS - 1);
        f16x4 hv;
#pragma unroll
        for (int r = 0; r < 4; ++r) hv[r] = (_Float16)(acc[i][j][r] + bv);
        *(f16x4*)&out[((size_t)((b * kH + h) * kD + d)) * kS + s] = hv;
      }
    }
  } else {
    const float osc = (blockIdx.z == 0) ? kQScale : 1.0f;
#pragma unroll
    for (int j = 0; j < 4; ++j) {
      int n = nbase + j * 16;
      float bv = bias[n];
      int h = n >> 6, d = n & 63;
#pragma unroll
      for (int i = 0; i < 4; ++i) {
        int mrow = mbase + i * 16;
#pragma unroll
        for (int r = 0; r < 4; ++r) {
          int m = mrow + r;
          int b = m >> 11, s = m & (kS - 1);
          out[(size_t)(((b * kH + h) * kS) + s) * kD + d] = (_Float16)((acc[i][j][r] + bv) * osc);
        }
      }
    }
  }
}

// ------------- flash attention, S^T formulation, v4 -------------
// R3 post-mortem: XOR swizzle was a phantom fix (bank conflicts are constant
// ~3.5 extra-cy per wide ds-op in BOTH layouts -- the pad-8 stride is already
// bank-uniform: +4 banks/row shift). What the XOR actually did was break
// base+immediate addressing (overlapping bits), adding v_xor/v_add per LDS
// access -> VALUBusy 40%. v4:
//  - pad-8 strides (136 f16 = 272B) for Vs/Pt: bank-uniform AND every LDS
//    address = loop-invariant base VGPR + compile-time immediate (zero VALU)
//  - s_setprio(1) around MFMA clusters (T5: measured +4-7% on attn)
//  - keep: K/V register prefetch, lgkm-only barriers, pens in LDS, XCD swizzle
__global__ __launch_bounds__(256, 2) void attn(
    const _Float16* __restrict__ Q, const _Float16* __restrict__ K,
    const _Float16* __restrict__ V, const float* __restrict__ mask,
    _Float16* __restrict__ ctx) {
  const int id = blockIdx.x;
  const int logical = (id & 7) * 64 + (id >> 3);
  const int bh = logical >> 4;    // 0..31
  const int qblk = logical & 15;  // 0..15
  const int b = bh >> 4;
  const int q0 = qblk * 128;
  const int tid = threadIdx.x, lane = tid & 63, wave = tid >> 6;
  const int l15 = lane & 15, quad = lane >> 4;

  __shared__ alignas(16) _Float16 Ks[128 * 72];     // [key][d], stride 144B
  __shared__ alignas(16) _Float16 Vs[64 * 136];     // [d][key], stride 272B
  __shared__ alignas(16) _Float16 Pt[4][32 * 136];  // per-wave P^T [q][key]
  __shared__ alignas(16) float pens[kS];            // (mask-1)*kPenC for all keys

  const _Float16* Qh = Q + (size_t)bh * kS * kD;
  const _Float16* Kh = K + (size_t)bh * kS * kD;
  const _Float16* Vh = V + (size_t)bh * kS * kD;  // [d][s]

  // mask penalties for the whole row, staged once (8KB)
#pragma unroll
  for (int i = 0; i < 2; ++i) {
    float4 mv4 = *(const float4*)&mask[(size_t)b * kS + tid * 8 + i * 4];
    float4 pv;
    pv.x = (mv4.x - 1.0f) * kPenC;
    pv.y = (mv4.y - 1.0f) * kPenC;
    pv.z = (mv4.z - 1.0f) * kPenC;
    pv.w = (mv4.w - 1.0f) * kPenC;
    *(float4*)&pens[tid * 8 + i * 4] = pv;
  }

  f16x8 qf[2][2];
#pragma unroll
  for (int t = 0; t < 2; ++t) {
    int qrow = q0 + wave * 32 + t * 16 + l15;
#pragma unroll
    for (int kk = 0; kk < 2; ++kk)
      qf[t][kk] = *(const f16x8*)&Qh[(size_t)qrow * kD + kk * 32 + quad * 8];
  }

  f32x4 o_acc[2][4] = {};   // O^T: [t][d-tile], C-layout (row=d, col=q)
  float l_part[2] = {0.0f, 0.0f};

  const int srow = tid >> 3;       // K staging row base
  const int skc = (tid & 7) * 8;   // K staging d-offset (f16)
  const int vrow = tid >> 4;       // V staging row base (c = tid+256i -> row = vrow+16i)
  const int vcol = (tid & 15) * 8; // V staging key-offset (f16)

  // prologue: prefetch first K/V tiles into registers
  f16x8 kreg[4], vreg[4];
#pragma unroll
  for (int i = 0; i < 4; ++i)
    kreg[i] = *(const f16x8*)&Kh[(size_t)(srow + 32 * i) * kD + skc];
#pragma unroll
  for (int i = 0; i < 4; ++i)
    vreg[i] = *(const f16x8*)&Vh[(size_t)(vrow + 16 * i) * kS + vcol];

  for (int it = 0; it < 16; ++it) {
    const int kb = it * 128;
    wg_barrier_lds();   // all waves done reading Ks/Vs from previous iter
#pragma unroll
    for (int i = 0; i < 4; ++i)
      *(f16x8*)&Ks[(srow + 32 * i) * 72 + skc] = kreg[i];
#pragma unroll
    for (int i = 0; i < 4; ++i)
      *(f16x8*)&Vs[(vrow + 16 * i) * 136 + vcol] = vreg[i];
    if (it + 1 < 16) {  // issue next K/V tiles; fly under compute (no vmcnt drain)
#pragma unroll
      for (int i = 0; i < 4; ++i)
        kreg[i] = *(const f16x8*)&Kh[(size_t)(kb + 128 + srow + 32 * i) * kD + skc];
#pragma unroll
      for (int i = 0; i < 4; ++i)
        vreg[i] = *(const f16x8*)&Vh[(size_t)(vrow + 16 * i) * kS + kb + 128 + vcol];
    }
    wg_barrier_lds();   // Ks/Vs ready

    // S^T = K Q^T per 16-key column-tile; exp2 with mask penalty; Pt store
#pragma unroll
    for (int colt = 0; colt < 8; ++colt) {
      f16x8 kf0 = *(const f16x8*)&Ks[(colt * 16 + l15) * 72 + quad * 8];
      f16x8 kf1 = *(const f16x8*)&Ks[(colt * 16 + l15) * 72 + 32 + quad * 8];
      f32x4 s0 = {}, s1 = {};
      __builtin_amdgcn_s_setprio(1);
      s0 = MFMA_16x16x32(kf0, qf[0][0], s0);
      s0 = MFMA_16x16x32(kf1, qf[0][1], s0);
      s1 = MFMA_16x16x32(kf0, qf[1][0], s1);
      s1 = MFMA_16x16x32(kf1, qf[1][1], s1);
      __builtin_amdgcn_s_setprio(0);
      f32x4 pn = *(const f32x4*)&pens[kb + colt * 16 + quad * 4];
      f16x4 ph0, ph1;
#pragma unroll
      for (int r = 0; r < 4; ++r) {
        float p0 = __builtin_exp2f(s0[r] + pn[r]);
        float p1 = __builtin_exp2f(s1[r] + pn[r]);
        l_part[0] += p0;
        l_part[1] += p1;
        ph0[r] = (_Float16)p0;
        ph1[r] = (_Float16)p1;
      }
      *(f16x4*)&Pt[wave][(l15) * 136 + colt * 16 + quad * 4] = ph0;
      *(f16x4*)&Pt[wave][(16 + l15) * 136 + colt * 16 + quad * 4] = ph1;
    }

    // O^T += V^T P^T (pad-8 layout: base+immediate addressing, bank-uniform)
#pragma unroll
    for (int ks = 0; ks < 4; ++ks) {
      f16x8 pf0 = *(const f16x8*)&Pt[wave][(l15) * 136 + ks * 32 + quad * 8];
      f16x8 pf1 = *(const f16x8*)&Pt[wave][(16 + l15) * 136 + ks * 32 + quad * 8];
      f16x8 vf0 = *(const f16x8*)&Vs[(0 * 16 + l15) * 136 + ks * 32 + quad * 8];
      f16x8 vf1 = *(const f16x8*)&Vs[(1 * 16 + l15) * 136 + ks * 32 + quad * 8];
      f16x8 vf2 = *(const f16x8*)&Vs[(2 * 16 + l15) * 136 + ks * 32 + quad * 8];
      f16x8 vf3 = *(const f16x8*)&Vs[(3 * 16 + l15) * 136 + ks * 32 + quad * 8];
      __builtin_amdgcn_s_setprio(1);
      o_acc[0][0] = MFMA_16x16x32(vf0, pf0, o_acc[0][0]);
      o_acc[1][0] = MFMA_16x16x32(vf0, pf1, o_acc[1][0]);
      o_acc[0][1] = MFMA_16x16x32(vf1, pf0, o_acc[0][1]);
      o_acc[1][1] = MFMA_16x16x32(vf1, pf1, o_acc[1][1]);
      o_acc[0][2] = MFMA_16x16x32(vf2, pf0, o_acc[0][2]);
      o_acc[1][2] = MFMA_16x16x32(vf2, pf1, o_acc[1][2]);
      o_acc[0][3] = MFMA_16x16x32(vf3, pf0, o_acc[0][3]);
      o_acc[1][3] = MFMA_16x16x32(vf3, pf1, o_acc[1][3]);
      __builtin_amdgcn_s_setprio(0);
    }
  }

  // epilogue: l(q) = reduce over quads; O^T lane holds 4 consecutive d for q=l15
  const int h = bh & 15;
#pragma unroll
  for (int t = 0; t < 2; ++t) {
    float lsum = l_part[t];
    lsum += __shfl_xor(lsum, 16, 64);
    lsum += __shfl_xor(lsum, 32, 64);
    float inv = 1.0f / lsum;
    int q = q0 + wave * 32 + t * 16 + l15;
#pragma unroll
    for (int c = 0; c < 4; ++c) {
      f16x4 oh;
#pragma unroll
      for (int r = 0; r < 4; ++r) oh[r] = (_Float16)(o_acc[t][c][r] * inv);
      *(f16x4*)&ctx[((size_t)(b * kS + q)) * kDim + h * kD + c * 16 + quad * 4] = oh;
    }
  }
}

// ------------- output GEMM (BK=64, double-buffered LDS, 1 barrier/iter) -------------
__global__ __launch_bounds__(256, 2) void gemm_out(
    const _Float16* __restrict__ A, const _Float16* __restrict__ Bt,
    const float* __restrict__ bias, float* __restrict__ out) {
  __shared__ alignas(16) _Float16 As[2][128 * 72];
  __shared__ alignas(16) _Float16 Bs[2][128 * 72];
  const int tid = threadIdx.x;
  const int lane = tid & 63;
  const int wave = tid >> 6;
  const int wm = wave & 1, wn = wave >> 1;
  const int l15 = lane & 15, quad = lane >> 4;
  const int m0 = blockIdx.x * 128, n0 = blockIdx.y * 128;

  const int srow = tid >> 3;
  const int skc = (tid & 7) * 8;

  f32x4 acc[4][4] = {};
  f16x8 ra[4], rb[4];

#pragma unroll
  for (int i = 0; i < 4; ++i) {
    int row = srow + 32 * i;
    ra[i] = *(const f16x8*)&A[(size_t)(m0 + row) * kDim + skc];
    rb[i] = *(const f16x8*)&Bt[(size_t)(n0 + row) * kDim + skc];
  }
#pragma unroll
  for (int i = 0; i < 4; ++i) {
    int row = srow + 32 * i;
    *(f16x8*)&As[0][row * 72 + skc] = ra[i];
    *(f16x8*)&Bs[0][row * 72 + skc] = rb[i];
  }

  for (int kt = 0; kt < 16; ++kt) {
    const int cur = kt & 1;
    if (kt + 1 < 16) {
      int k0 = (kt + 1) * 64;
#pragma unroll
      for (int i = 0; i < 4; ++i) {
        int row = srow + 32 * i;
        ra[i] = *(const f16x8*)&A[(size_t)(m0 + row) * kDim + k0 + skc];
        rb[i] = *(const f16x8*)&Bt[(size_t)(n0 + row) * kDim + k0 + skc];
      }
    }
    wg_barrier_lds();
#pragma unroll
    for (int kk = 0; kk < 2; ++kk) {
      f16x8 af[4], bf[4];
#pragma unroll
      for (int t = 0; t < 4; ++t) af[t] = *(const f16x8*)&As[cur][(wm * 64 + t * 16 + l15) * 72 + kk * 32 + quad * 8];
#pragma unroll
      for (int t = 0; t < 4; ++t) bf[t] = *(const f16x8*)&Bs[cur][(wn * 64 + t * 16 + l15) * 72 + kk * 32 + quad * 8];
      __builtin_amdgcn_s_setprio(1);
#pragma unroll
      for (int i = 0; i < 4; ++i)
#pragma unroll
        for (int j = 0; j < 4; ++j)
          acc[i][j] = MFMA_16x16x32(af[i], bf[j], acc[i][j]);
      __builtin_amdgcn_s_setprio(0);
    }
    if (kt + 1 < 16) {
#pragma unroll
      for (int i = 0; i < 4; ++i) {
        int row = srow + 32 * i;
        *(f16x8*)&As[cur ^ 1][row * 72 + skc] = ra[i];
        *(f16x8*)&Bs[cur ^ 1][row * 72 + skc] = rb[i];
      }
    }
  }

  const int mbase = m0 + wm * 64 + quad * 4;
  const int nbase = n0 + wn * 64 + l15;
#pragma unroll
  for (int j = 0; j < 4; ++j) {
    int n = nbase + j * 16;
    float bv = bias[n];
#pragma unroll
    for (int i = 0; i < 4; ++i) {
      int mrow = mbase + i * 16;
#pragma unroll
      for (int r = 0; r < 4; ++r)
        out[(size_t)(mrow + r) * kDim + n] = acc[i][j][r] + bv;
    }
  }
}

extern "C" void kernel_launch(void* const* d_in, const int* in_sizes, int n_in,
                              void* d_out, int out_size, void* d_ws, size_t ws_size,
                              hipStream_t stream) {
  (void)in_sizes; (void)n_in; (void)out_size; (void)ws_size;
  const float* X    = (const float*)d_in[0];
  const float* mask = (const float*)d_in[1];
  const float* Wq   = (const float*)d_in[2];
  const float* bq   = (const float*)d_in[3];
  const float* Wk   = (const float*)d_in[4];
  const float* bk   = (const float*)d_in[5];
  const float* Wv   = (const float*)d_in[6];
  const float* bv   = (const float*)d_in[7];
  const float* Wo   = (const float*)d_in[8];
  const float* bo   = (const float*)d_in[9];
  float* out = (float*)d_out;

  char* ws = (char*)d_ws;
  _Float16* Xh   = (_Float16*)(ws);                        // 8 MB
  _Float16* Wqt  = (_Float16*)(ws + ((size_t)8  << 20));   // 2 MB each
  _Float16* Wkt  = (_Float16*)(ws + ((size_t)10 << 20));
  _Float16* Wvt  = (_Float16*)(ws + ((size_t)12 << 20));
  _Float16* Wot  = (_Float16*)(ws + ((size_t)14 << 20));
  _Float16* Qh   = (_Float16*)(ws + ((size_t)16 << 20));   // 8 MB each
  _Float16* Kh   = (_Float16*)(ws + ((size_t)24 << 20));
  _Float16* Vh   = (_Float16*)(ws + ((size_t)32 << 20));   // [B][H][D][S]
  _Float16* Ch   = (_Float16*)(ws + ((size_t)40 << 20));   // 8 MB

  cvt_f32_to_f16<<<dim3(kM * kDim / 8 / 256), dim3(256), 0, stream>>>(X, Xh, kM * kDim / 8);
  transpose_cvt_w<<<dim3(16, 16, 4), dim3(256), 0, stream>>>(Wq, Wk, Wv, Wo, Wqt, Wkt, Wvt, Wot);
  gemm_qkv<<<dim3(32, 8, 3), dim3(256), 0, stream>>>(Xh, Wqt, Wkt, Wvt, bq, bk, bv, Qh, Kh, Vh);
  attn<<<dim3(512), dim3(256), 0, stream>>>(Qh, Kh, Vh, mask, Ch);
  gemm_out<<<dim3(32, 8), dim3(256), 0, stream>>>(Ch, Wot, bo, out);
}